// Round 15
// baseline (251.412 us; speedup 1.0000x reference)
//
#include <hip/hip_runtime.h>

// LSH attention, B=4, T=4096, D=512, H=8 hashes, 64 buckets/hash, bucket size 64.
// Round 15: revert T5 setprio in attn (regression: our attn is 4-wave lockstep
// = m190's null/negative regime, not m191's independent-wave regime). Keep the
// round-14 rot3-into-qkv fusion (A/B vs round 13 disambiguates it).

typedef __attribute__((ext_vector_type(8))) short short8;
typedef __attribute__((ext_vector_type(4))) float f32x4;
typedef unsigned short ushort_t;

__device__ __forceinline__ ushort_t f2b(float f) {
  union { float f; unsigned u; } x; x.f = f;
  unsigned r = x.u + 0x7fffu + ((x.u >> 16) & 1u);
  return (ushort_t)(r >> 16);
}
__device__ __forceinline__ float b2f(unsigned b) {
  union { unsigned u; float f; } x; x.u = b << 16;
  return x.f;
}
__device__ __forceinline__ void gload16(void* lds, const void* gp) {
  __builtin_amdgcn_global_load_lds(
      (const __attribute__((address_space(1))) unsigned int*)gp,
      (__attribute__((address_space(3))) unsigned int*)lds, 16, 0, 0);
}

// -------- fused prep: split_x | transpose_cvt x3 | w2_split | mcount=0 --------
__global__ __launch_bounds__(256) void prep_kernel(
    const float* __restrict__ x, const float* __restrict__ w_qk,
    const float* __restrict__ b_qk, const float* __restrict__ R,
    const float* __restrict__ w_v, const float* __restrict__ w_out,
    ushort_t* __restrict__ xh, ushort_t* __restrict__ xl,
    ushort_t* __restrict__ wqkT, ushort_t* __restrict__ wvT, ushort_t* __restrict__ woT,
    ushort_t* __restrict__ W2Th, ushort_t* __restrict__ W2Tl, float* __restrict__ b2,
    int* __restrict__ mcount)
{
  __shared__ float t[32][33];
  __shared__ float wrow[512];
  const int blk = blockIdx.x, tid = threadIdx.x;
  if (blk == 0 && tid == 0) mcount[0] = 0;

  if (blk < 4096) {                      // ---- split_x ----
    const int i = blk * 256 + tid;
    const float4 a = *(const float4*)(x + (size_t)i * 8);
    const float4 c = *(const float4*)(x + (size_t)i * 8 + 4);
    float v[8] = { a.x, a.y, a.z, a.w, c.x, c.y, c.z, c.w };
    ushort_t hi[8], lo[8];
    #pragma unroll
    for (int k = 0; k < 8; ++k) {
      hi[k] = f2b(v[k]);
      lo[k] = f2b(v[k] - b2f(hi[k]));
    }
    *(uint4*)(xh + (size_t)i * 8) = *(const uint4*)hi;
    *(uint4*)(xl + (size_t)i * 8) = *(const uint4*)lo;
  } else if (blk < 4864) {               // ---- transpose_cvt x3 ----
    const int idx = blk - 4096;
    const int mat = idx >> 8, r = idx & 255;
    const float* W  = (mat == 0) ? w_qk : (mat == 1) ? w_v : w_out;
    ushort_t*   Wt  = (mat == 0) ? wqkT : (mat == 1) ? wvT : woT;
    const int bx = (r & 15) * 32, by = (r >> 4) * 32;
    const int tx = tid & 31, ty = tid >> 5;
    #pragma unroll
    for (int j = 0; j < 4; ++j)
      t[ty + j*8][tx] = W[(size_t)(by + ty + j*8) * 512 + bx + tx];
    __syncthreads();
    #pragma unroll
    for (int j = 0; j < 4; ++j)
      Wt[(size_t)(bx + ty + j*8) * 512 + by + tx] = f2b(t[tx][ty + j*8]);
  } else {                               // ---- w2_split ----
    const int e = blk - 4864, j = tid;   // e in [0,513), j in [0,256)
    const float* src = (e < 512) ? (w_qk + (size_t)e * 512) : b_qk;
    wrow[j]       = src[j];
    wrow[j + 256] = src[j + 256];
    __syncthreads();
    float acc = 0.f;
    for (int f = 0; f < 512; ++f)
      acc = fmaf(wrow[f], R[(size_t)f * 256 + j], acc);
    if (e < 512) {
      const ushort_t hi = f2b(acc);
      W2Th[(size_t)j * 512 + e] = hi;
      W2Tl[(size_t)j * 512 + e] = f2b(acc - b2f(hi));
    } else {
      b2[j] = acc;
    }
  }
}

// ---- fused qk+v GEMM + rot3 in one launch ----
// grid (128, 10): y<4 -> qk col-block; y<8 -> v col-block; y>=8 -> rot3 bn=(y-8)*128.
__global__ __launch_bounds__(256, 2) void gemm_qkvr(
    const ushort_t* __restrict__ A, const ushort_t* __restrict__ Axl,
    const ushort_t* __restrict__ wqkT, const ushort_t* __restrict__ wvT,
    const float* __restrict__ b_qk, const float* __restrict__ b_v,
    ushort_t* __restrict__ qkv,
    const ushort_t* __restrict__ W2Th, const ushort_t* __restrict__ W2Tl,
    const float* __restrict__ b2, float* __restrict__ rot)
{
  __shared__ __align__(16) char lds[65536];
  const int bm = blockIdx.x * 128;
  const int tid = threadIdx.x, w = tid >> 6, l = tid & 63;
  const int m = l & 15, gq = l >> 4;

  if (blockIdx.y < 8) {
    // ================= qk / v GEMM (dbuf stage-ahead) =================
    char* Al = lds;
    char* Bl = lds + 32768;
    const int sel = blockIdx.y >> 2;           // 0 = qk, 1 = v
    const int bn = (blockIdx.y & 3) * 128;
    const ushort_t* Wt   = sel ? wvT : wqkT;
    const float*    bias = sel ? b_v : b_qk;
    const int coff = sel * 512;
    f32x4 acc[2][8] = {};

#define STAGE1(NB, K0) { \
    _Pragma("unroll") \
    for (int j = 0; j < 4; ++j) { \
      const int row = w * 32 + j * 8 + (l >> 3); \
      const int ch = (l & 7) ^ (row & 7); \
      const int dst = (NB) * 16384 + w * 4096 + j * 1024 + l * 16; \
      gload16(Al + dst, A  + (size_t)(bm + row) * 512 + (K0) + ch * 8); \
      gload16(Bl + dst, Wt + (size_t)(bn + row) * 512 + (K0) + ch * 8); \
    } }

    STAGE1(0, 0)
    __syncthreads();
    for (int t = 0; t < 8; ++t) {
      const int cur = t & 1;
      if (t < 7) STAGE1(cur ^ 1, (t + 1) * 64)
      #pragma unroll
      for (int ks = 0; ks < 2; ++ks) {
        short8 bfr[8];
        #pragma unroll
        for (int tj = 0; tj < 8; ++tj) {
          const int brow = tj * 16 + m;
          bfr[tj] = *(const short8*)(Bl + cur * 16384 + ((brow * 128 + ks * 64 + gq * 16) ^ ((brow & 7) << 4)));
        }
        #pragma unroll
        for (int ti = 0; ti < 2; ++ti) {
          const int arow = w * 32 + ti * 16 + m;
          const short8 af = *(const short8*)(Al + cur * 16384 + ((arow * 128 + ks * 64 + gq * 16) ^ ((arow & 7) << 4)));
          #pragma unroll
          for (int tj = 0; tj < 8; ++tj)
            acc[ti][tj] = __builtin_amdgcn_mfma_f32_16x16x32_bf16(af, bfr[tj], acc[ti][tj], 0, 0, 0);
        }
      }
      __syncthreads();
    }
#undef STAGE1
    #pragma unroll
    for (int ti = 0; ti < 2; ++ti)
      #pragma unroll
      for (int tj = 0; tj < 8; ++tj) {
        const int col = bn + tj * 16 + m;
        const float bvv = bias[col];
        #pragma unroll
        for (int r2 = 0; r2 < 4; ++r2) {
          const int row = bm + w * 32 + ti * 16 + gq * 4 + r2;
          qkv[(size_t)row * 1024 + coff + col] = f2b(acc[ti][tj][r2] + bvv);
        }
      }
  } else {
    // ================= rot3 (3-product split-bf16) =================
    char* AH = lds;
    char* AL = lds + 16384;
    char* BH = lds + 32768;
    char* BL = lds + 49152;
    const int bn = (blockIdx.y - 8) * 128;
    f32x4 acc[2][8] = {};
    for (int k0 = 0; k0 < 512; k0 += 64) {
      #pragma unroll
      for (int j = 0; j < 4; ++j) {
        const int row = w * 32 + j * 8 + (l >> 3);
        const int ch = (l & 7) ^ (row & 7);
        const int dst = w * 4096 + j * 1024 + l * 16;
        gload16(AH + dst, A    + (size_t)(bm + row) * 512 + k0 + ch * 8);
        gload16(AL + dst, Axl  + (size_t)(bm + row) * 512 + k0 + ch * 8);
        gload16(BH + dst, W2Th + (size_t)(bn + row) * 512 + k0 + ch * 8);
        gload16(BL + dst, W2Tl + (size_t)(bn + row) * 512 + k0 + ch * 8);
      }
      __syncthreads();
      #pragma unroll
      for (int ks = 0; ks < 2; ++ks) {
        short8 bh8[8], bl8[8];
        #pragma unroll
        for (int tj = 0; tj < 8; ++tj) {
          const int ba = ((tj * 16 + m) * 128 + ks * 64 + gq * 16) ^ (((tj * 16 + m) & 7) << 4);
          bh8[tj] = *(const short8*)(BH + ba);
          bl8[tj] = *(const short8*)(BL + ba);
        }
        #pragma unroll
        for (int ti = 0; ti < 2; ++ti) {
          const int arow = w * 32 + ti * 16 + m;
          const int aa = (arow * 128 + ks * 64 + gq * 16) ^ ((arow & 7) << 4);
          const short8 ah8 = *(const short8*)(AH + aa);
          const short8 al8 = *(const short8*)(AL + aa);
          #pragma unroll
          for (int tj = 0; tj < 8; ++tj) {
            acc[ti][tj] = __builtin_amdgcn_mfma_f32_16x16x32_bf16(ah8, bh8[tj], acc[ti][tj], 0, 0, 0);
            acc[ti][tj] = __builtin_amdgcn_mfma_f32_16x16x32_bf16(al8, bh8[tj], acc[ti][tj], 0, 0, 0);
            acc[ti][tj] = __builtin_amdgcn_mfma_f32_16x16x32_bf16(ah8, bl8[tj], acc[ti][tj], 0, 0, 0);
          }
        }
      }
      __syncthreads();
    }
    #pragma unroll
    for (int ti = 0; ti < 2; ++ti)
      #pragma unroll
      for (int tj = 0; tj < 8; ++tj) {
        const int col = bn + tj * 16 + m;
        const float bvv = b2[col];
        #pragma unroll
        for (int r2 = 0; r2 < 4; ++r2) {
          const int row = bm + w * 32 + ti * 16 + gq * 4 + r2;
          rot[(size_t)row * 256 + col] = acc[ti][tj][r2] + bvv;
        }
      }
  }
}

// ---- bf16 MFMA GEMM (1 product), dbuf; used for the out GEMM (fp32 out) ----
__global__ __launch_bounds__(256, 2) void gemm_mfma(
    const ushort_t* __restrict__ A, const ushort_t* __restrict__ Wt,
    const float* __restrict__ bias, float* __restrict__ Cf)
{
  __shared__ __align__(16) char Al[32768];
  __shared__ __align__(16) char Bl[32768];
  const int bm = blockIdx.x * 128, bn = blockIdx.y * 128;
  const int tid = threadIdx.x, w = tid >> 6, l = tid & 63;
  const int m = l & 15, gq = l >> 4;
  f32x4 acc[2][8] = {};

#define STAGE1(NB, K0) { \
    _Pragma("unroll") \
    for (int j = 0; j < 4; ++j) { \
      const int row = w * 32 + j * 8 + (l >> 3); \
      const int ch = (l & 7) ^ (row & 7); \
      const int dst = (NB) * 16384 + w * 4096 + j * 1024 + l * 16; \
      gload16(Al + dst, A  + (size_t)(bm + row) * 512 + (K0) + ch * 8); \
      gload16(Bl + dst, Wt + (size_t)(bn + row) * 512 + (K0) + ch * 8); \
    } }

  STAGE1(0, 0)
  __syncthreads();
  for (int t = 0; t < 8; ++t) {
    const int cur = t & 1;
    if (t < 7) STAGE1(cur ^ 1, (t + 1) * 64)
    #pragma unroll
    for (int ks = 0; ks < 2; ++ks) {
      short8 bfr[8];
      #pragma unroll
      for (int tj = 0; tj < 8; ++tj) {
        const int brow = tj * 16 + m;
        bfr[tj] = *(const short8*)(Bl + cur * 16384 + ((brow * 128 + ks * 64 + gq * 16) ^ ((brow & 7) << 4)));
      }
      #pragma unroll
      for (int ti = 0; ti < 2; ++ti) {
        const int arow = w * 32 + ti * 16 + m;
        const short8 af = *(const short8*)(Al + cur * 16384 + ((arow * 128 + ks * 64 + gq * 16) ^ ((arow & 7) << 4)));
        #pragma unroll
        for (int tj = 0; tj < 8; ++tj)
          acc[ti][tj] = __builtin_amdgcn_mfma_f32_16x16x32_bf16(af, bfr[tj], acc[ti][tj], 0, 0, 0);
      }
    }
    __syncthreads();
  }
#undef STAGE1
  #pragma unroll
  for (int ti = 0; ti < 2; ++ti)
    #pragma unroll
    for (int tj = 0; tj < 8; ++tj) {
      const int col = bn + tj * 16 + m;
      const float bvv = bias[col];
      #pragma unroll
      for (int r2 = 0; r2 < 4; ++r2) {
        const int row = bm + w * 32 + ti * 16 + gq * 4 + r2;
        Cf[(size_t)row * 512 + col] = acc[ti][tj][r2] + bvv;
      }
    }
}

// ---- fused: argmax+margin (blocks < 16384) | scale (blocks >= 16384) ----
__global__ __launch_bounds__(256) void argmax_scale(
    const float* __restrict__ rot, int* __restrict__ buckets,
    int* __restrict__ mlist, int* __restrict__ mcount, float tau,
    const ushort_t* __restrict__ qkv, float* __restrict__ scale)
{
  const int blk = blockIdx.x;
  if (blk < 16384) {
    const int tok = blk;
    const int j = threadIdx.x;             // j = h*32 + i
    const float r = rot[(size_t)tok * 256 + j];
    float m1, m2; int i1;
    if (r >= 0.f) { m1 = r;  i1 = j & 31;        m2 = -r; }
    else          { m1 = -r; i1 = (j & 31) + 32; m2 = r;  }
    #pragma unroll
    for (int off = 16; off; off >>= 1) {
      const float om1 = __shfl_xor(m1, off);
      const int   oi1 = __shfl_xor(i1, off);
      const float om2 = __shfl_xor(m2, off);
      float loser;
      if (om1 > m1 || (om1 == m1 && oi1 < i1)) { loser = m1; m1 = om1; i1 = oi1; }
      else loser = om1;
      m2 = fmaxf(fmaxf(m2, om2), loser);
    }
    if ((j & 31) == 0) {
      const int h = j >> 5, b = tok >> 12, t = tok & 4095;
      buckets[((b << 3) + h) * 4096 + t] = i1;
      if (m1 - m2 < tau) {
        const int k = atomicAdd(mcount, 1);
        mlist[k] = (((b << 3) + h) << 12) | t;
      }
    }
  } else {
    const int wave = threadIdx.x >> 6, lane = threadIdx.x & 63;
    const int tok = (blk - 16384) * 4 + wave;
    const uint4 H = *(const uint4*)(qkv + (size_t)tok * 1024 + lane * 8);
    const unsigned* hp = (const unsigned*)&H;
    float s = 0.f;
    #pragma unroll
    for (int e = 0; e < 4; ++e) {
      const float v0 = b2f(hp[e] & 0xffffu);
      const float v1 = b2f(hp[e] >> 16);
      s += v0 * v0 + v1 * v1;
    }
    #pragma unroll
    for (int off = 32; off; off >>= 1) s += __shfl_down(s, off);
    if (lane == 0) {
      const float nn = fmaxf(sqrtf(s), 1e-12f);
      scale[tok] = 0.044194173824159216f / nn;   // 512^-0.5 / norm
    }
  }
}

// ---- exact np-chain fallback for marginal (b,h,t) pairs ----
__global__ __launch_bounds__(512) void bucket_fallback(
    const float* __restrict__ x, const float* __restrict__ w_qk,
    const float* __restrict__ b_qk, const float* __restrict__ R,
    const int* __restrict__ mlist, const int* __restrict__ mcount,
    int* __restrict__ buckets)
{
  __shared__ float qkrow[512];
  const int n = mcount[0];
  for (int ii = blockIdx.x; ii < n; ii += gridDim.x) {
    const int mm = mlist[ii];
    const int bh = mm >> 12, t = mm & 4095;
    const int b = bh >> 3, h = bh & 7;
    const float* xr = x + ((size_t)b * 4096 + t) * 512;
    {
      const int c = threadIdx.x;
      float a0 = 0.f;
      for (int f = 0; f < 512; ++f) a0 = fmaf(xr[f], w_qk[(size_t)f * 512 + c], a0);
      qkrow[c] = a0 + b_qk[c];
    }
    __syncthreads();
    if (threadIdx.x < 32) {
      const int col = h * 32 + threadIdx.x;
      float a0 = 0.f;
      for (int f = 0; f < 512; ++f) a0 = fmaf(qkrow[f], R[(size_t)f * 256 + col], a0);
      float m1; int i1;
      if (a0 >= 0.f) { m1 = a0;  i1 = threadIdx.x; }
      else           { m1 = -a0; i1 = threadIdx.x + 32; }
      #pragma unroll
      for (int off = 16; off; off >>= 1) {
        const float om = __shfl_xor(m1, off);
        const int   oi = __shfl_xor(i1, off);
        if (om > m1 || (om == m1 && oi < i1)) { m1 = om; i1 = oi; }
      }
      if (threadIdx.x == 0) buckets[(size_t)bh * 4096 + t] = i1;
    }
    __syncthreads();
  }
}

// -------- stable counting sort per (b,h), wave-parallel via 6-ballot match --------
__global__ __launch_bounds__(256) void sort_kernel(
    const int* __restrict__ buckets, int* __restrict__ st)
{
  __shared__ int bk_lds[4096];
  __shared__ int cnt[64][64];
  __shared__ int bstart[64];
  const int tid = threadIdx.x;
  const int base = blockIdx.x * 4096;     // blockIdx = b*8+h
  const int wave = tid >> 6, lane = tid & 63;
  const unsigned long long lt = (1ull << lane) - 1ull;

  for (int t = tid; t < 4096; t += 256) bk_lds[t] = buckets[base + t];
  for (int i = tid; i < 4096; i += 256) ((int*)cnt)[i] = 0;
  __syncthreads();

  for (int c = wave; c < 64; c += 4) {
    const int bk = bk_lds[c * 64 + lane];
    unsigned long long mask = ~0ull;
    #pragma unroll
    for (int bit = 0; bit < 6; ++bit) {
      const unsigned long long bb = __ballot((bk >> bit) & 1);
      mask &= ((bk >> bit) & 1) ? bb : ~bb;
    }
    if ((mask & lt) == 0)
      cnt[c][bk] = __popcll(mask);
  }
  __syncthreads();

  if (tid < 64) {
    int run = 0;
    for (int c = 0; c < 64; ++c) {
      const int v = cnt[c][tid];
      cnt[c][tid] = run;
      run += v;
    }
    int ex = run;
    #pragma unroll
    for (int off = 1; off < 64; off <<= 1) {
      const int nn = __shfl_up(ex, off);
      if (lane >= off) ex += nn;
    }
    bstart[tid] = ex - run;
  }
  __syncthreads();

  for (int c = wave; c < 64; c += 4) {
    const int tok = c * 64 + lane;
    const int bk = bk_lds[tok];
    unsigned long long mask = ~0ull;
    #pragma unroll
    for (int bit = 0; bit < 6; ++bit) {
      const unsigned long long bb = __ballot((bk >> bit) & 1);
      mask &= ((bk >> bit) & 1) ? bb : ~bb;
    }
    const int rank = (int)__popcll(mask & lt);
    st[base + bstart[bk] + cnt[c][bk] + rank] = tok;
  }
}

// -------- MFMA chunked attention: interleaved qkv, T14 stage-ahead (no setprio) --------
__global__ __launch_bounds__(256, 2) void attn_mfma(
    const ushort_t* __restrict__ qkv, const float* __restrict__ scale,
    const int* __restrict__ st, ushort_t* __restrict__ so, int g, int hbase)
{
  __shared__ __align__(16) char Q[32768];
  __shared__ __align__(16) char VT[32768];
  __shared__ __align__(16) char P[8192];
  __shared__ int   stt[64];
  __shared__ float scl[64];

  const int blk = blockIdx.x;
  const int cpg = g * 64;
  const int b = blk / cpg, rem = blk % cpg;
  const int hl = rem >> 6, c = rem & 63;
  const int tid = threadIdx.x, w = tid >> 6, l = tid & 63;
  const int m = l & 15, gq = l >> 4;
  const int srow = tid >> 5, su = tid & 31;

  if (tid < 64) {
    const int s = st[(size_t)((b * 8 + hbase + hl) * 4096) + c * 64 + tid];
    stt[tid] = s;
    scl[tid] = scale[b * 4096 + s];
  }
  __syncthreads();

  const size_t qkbase = (size_t)b * 4096;
  uint4 rg[8];

#define LOADG(VOFF, HALF) { \
    _Pragma("unroll") \
    for (int it = 0; it < 8; ++it) { \
      const int row = it * 8 + srow; \
      rg[it] = *(const uint4*)(qkv + (qkbase + stt[row]) * 1024 + (VOFF) + (HALF) * 256 + su * 8); \
    } }
#define WRITEQ() { \
    _Pragma("unroll") \
    for (int it = 0; it < 8; ++it) { \
      const int row = it * 8 + srow; \
      *(uint4*)(Q + ((row * 512 + su * 16) ^ ((row & 7) << 4))) = rg[it]; \
    } }
#define WRITEVT() { \
    _Pragma("unroll") \
    for (int it = 0; it < 8; ++it) { \
      const int j = it * 8 + srow; \
      const ushort_t* e = (const ushort_t*)&rg[it]; \
      _Pragma("unroll") \
      for (int ee = 0; ee < 8; ++ee) { \
        const int d = su * 8 + ee; \
        *(ushort_t*)(VT + ((d * 128 + j * 2) ^ (((d ^ (d >> 3)) & 7) << 4))) = e[ee]; \
      } \
    } }
#define COMPUTE_S() { \
    _Pragma("unroll") \
    for (int kf = 0; kf < 8; ++kf) { \
      const int arow = w * 16 + m; \
      const short8 af = *(const short8*)(Q + ((arow * 512 + kf * 64 + gq * 16) ^ ((arow & 7) << 4))); \
      _Pragma("unroll") \
      for (int jt = 0; jt < 4; ++jt) { \
        const int brow = jt * 16 + m; \
        const short8 bf = *(const short8*)(Q + ((brow * 512 + kf * 64 + gq * 16) ^ ((brow & 7) << 4))); \
        accS[jt] = __builtin_amdgcn_mfma_f32_16x16x32_bf16(af, bf, accS[jt], 0, 0, 0); \
      } \
    } }
#define COMPUTE_PV(ACCO) { \
    _Pragma("unroll") \
    for (int dt = 0; dt < 16; ++dt) { \
      _Pragma("unroll") \
      for (int kf = 0; kf < 2; ++kf) { \
        const int d = dt * 16 + m; \
        const short8 bv = *(const short8*)(VT + ((d * 128 + kf * 64 + gq * 16) ^ (((d ^ (d >> 3)) & 7) << 4))); \
        ACCO[dt] = __builtin_amdgcn_mfma_f32_16x16x32_bf16(ap[kf], bv, ACCO[dt], 0, 0, 0); \
      } \
    } }
#define BOUNCE(ACCO) { \
    _Pragma("unroll") \
    for (int dt = 0; dt < 16; ++dt) \
      _Pragma("unroll") \
      for (int r = 0; r < 4; ++r) { \
        const int i = w * 16 + gq * 4 + r; \
        const int dcol = dt * 16 + m; \
        *(ushort_t*)(Q + ((i * 512 + dcol * 2) ^ ((i & 7) << 4))) = f2b(ACCO[dt][r]); \
      } }
#define FLUSH(HALF) { \
    _Pragma("unroll") \
    for (int it = 0; it < 8; ++it) { \
      const int row = it * 8 + srow; \
      const uint4 dat = *(const uint4*)(Q + ((row * 512 + su * 16) ^ ((row & 7) << 4))); \
      *(uint4*)(so + (sobase + stt[row]) * 512 + (HALF) * 256 + su * 8) = dat; \
    } }

  f32x4 accS[4] = {};

  LOADG(0, 0)
  WRITEQ()
  __syncthreads();
  LOADG(0, 1)
  COMPUTE_S()
  __syncthreads();
  WRITEQ()
  __syncthreads();
  LOADG(512, 0)
  COMPUTE_S()
  __syncthreads();

  #pragma unroll
  for (int jt = 0; jt < 4; ++jt)
    #pragma unroll
    for (int r = 0; r < 4; ++r) {
      const int i = w * 16 + gq * 4 + r;
      const int j = jt * 16 + m;
      *(ushort_t*)(P + ((i * 128 + j * 2) ^ ((i & 7) << 4))) = f2b(accS[jt][r] * scl[j]);
    }
  WRITEVT()
  __syncthreads();

  const size_t sobase = (size_t)(b * g + hl) * 4096;
  LOADG(512, 1)
  short8 ap[2];
  #pragma unroll
  for (int kf = 0; kf < 2; ++kf) {
    const int i = w * 16 + m;
    ap[kf] = *(const short8*)(P + ((i * 128 + kf * 64 + gq * 16) ^ ((i & 7) << 4)));
  }
  f32x4 accO[16] = {};
  COMPUTE_PV(accO)
  __syncthreads();

  WRITEVT()
  BOUNCE(accO)
  __syncthreads();

  FLUSH(0)
  f32x4 accO2[16] = {};
  COMPUTE_PV(accO2)
  __syncthreads();

  BOUNCE(accO2)
  __syncthreads();
  FLUSH(1)

#undef LOADG
#undef WRITEQ
#undef WRITEVT
#undef COMPUTE_S
#undef COMPUTE_PV
#undef BOUNCE
#undef FLUSH
}

// -------- gather: o_b[tok][:] (+)= sum_{hl<g} so[(b*g+hl)*4096 + t][:], bf16 --------
__global__ __launch_bounds__(256) void gather_kernel(
    const ushort_t* __restrict__ so, ushort_t* __restrict__ o_b, int g, int first)
{
  const int tok = blockIdx.x;
  const int b = tok >> 12, t = tok & 4095;
  const int d0 = threadIdx.x * 2;
  ushort_t* dst = o_b + (size_t)tok * 512 + d0;
  float ax = 0.f, ay = 0.f;
  if (!first) {
    const unsigned u = *(const unsigned*)dst;
    ax = b2f(u & 0xffffu); ay = b2f(u >> 16);
  }
  const size_t stride = (size_t)4096 * 512;
  const ushort_t* src = so + ((size_t)(b * g) * 4096 + t) * 512 + d0;
  for (int hlp = 0; hlp < g; ++hlp) {
    const unsigned u = *(const unsigned*)src;
    ax += b2f(u & 0xffffu);
    ay += b2f(u >> 16);
    src += stride;
  }
  *(unsigned*)dst = ((unsigned)f2b(ay) << 16) | (unsigned)f2b(ax);
}

extern "C" void kernel_launch(void* const* d_in, const int* in_sizes, int n_in,
                              void* d_out, int out_size, void* d_ws, size_t ws_size,
                              hipStream_t stream) {
  const float* x         = (const float*)d_in[0];
  const float* rotations = (const float*)d_in[1];
  const float* w_qk      = (const float*)d_in[2];
  const float* b_qk      = (const float*)d_in[3];
  const float* w_v       = (const float*)d_in[4];
  const float* b_v       = (const float*)d_in[5];
  const float* w_out     = (const float*)d_in[6];
  const float* b_out     = (const float*)d_in[7];
  float* out = (float*)d_out;
  char* ws = (char*)d_ws;

  ushort_t* xh      = (ushort_t*)(ws);                  // 16.78 MB
  ushort_t* xl      = (ushort_t*)(ws + 16777216);       // 16.78 MB
  ushort_t* qkv     = (ushort_t*)(ws + 33554432);       // 33.55 MB (qk|v interleaved, 2KB/token)
  float*    rot     = (float*)(ws + 67108864);          // 16.78 MB (dead after fallback)
  ushort_t* o_b     = (ushort_t*)(ws + 67108864);       // alias: lives after gather
  ushort_t* wqkTh   = (ushort_t*)(ws + 83886080);       // 512 KB
  ushort_t* wvT     = (ushort_t*)(ws + 84410368);       // 512 KB
  ushort_t* woT     = (ushort_t*)(ws + 84934656);       // 512 KB
  ushort_t* W2Th    = (ushort_t*)(ws + 85458944);       // 256 KB
  ushort_t* W2Tl    = (ushort_t*)(ws + 85721088);       // 256 KB
  float*    b2      = (float*)(ws + 85983232);          // 1 KB (pad to 4K)
  float*    scale   = (float*)(ws + 85987328);          // 64 KB
  int*      buckets = (int*)(ws + 86052864);            // 512 KB
  int*      st      = (int*)(ws + 86577152);            // 512 KB
  int*      mlist   = (int*)(ws + 87101440);            // 512 KB (cap 131072: can't overflow)
  int*      mcount  = (int*)(ws + 87625728);            // 4 KB
  ushort_t* so      = (ushort_t*)(ws + 87629824);       // g * 16.78 MB
  const size_t so_off = 87629824;

  int g = 1;
  for (int cand = 8; cand >= 1; cand >>= 1)
    if (so_off + (size_t)cand * 16777216ull <= ws_size) { g = cand; break; }

  const dim3 blk256(256);
  hipLaunchKernelGGL(prep_kernel, dim3(5377), blk256, 0, stream,
                     x, w_qk, b_qk, rotations, w_v, w_out,
                     xh, xl, wqkTh, wvT, woT, W2Th, W2Tl, b2, mcount);

  hipLaunchKernelGGL(gemm_qkvr, dim3(128, 10), blk256, 0, stream,
                     xh, xl, wqkTh, wvT, b_qk, b_v, qkv, W2Th, W2Tl, b2, rot);

  hipLaunchKernelGGL(argmax_scale, dim3(20480), blk256, 0, stream,
                     rot, buckets, mlist, mcount, 1.5e-3f, qkv, scale);
  hipLaunchKernelGGL(bucket_fallback, dim3(1024), dim3(512), 0, stream,
                     x, w_qk, b_qk, rotations, mlist, mcount, buckets);
  hipLaunchKernelGGL(sort_kernel, dim3(32), blk256, 0, stream, buckets, st);

  const int passes = 8 / g;
  for (int p = 0; p < passes; ++p) {
    const int hbase = p * g;
    hipLaunchKernelGGL(attn_mfma, dim3(4 * g * 64), blk256, 0, stream,
                       qkv, scale, st, so, g, hbase);
    hipLaunchKernelGGL(gather_kernel, dim3(16384), blk256, 0, stream,
                       so, o_b, g, (p == 0) ? 1 : 0);
  }

  hipLaunchKernelGGL(gemm_mfma, dim3(128, 4), blk256, 0, stream, o_b, woT, b_out, out);
}

// Round 16
// 243.879 us; speedup vs baseline: 1.0309x; 1.0309x over previous
//
#include <hip/hip_runtime.h>

// LSH attention, B=4, T=4096, D=512, H=8 hashes, 64 buckets/hash, bucket size 64.
// Round 16: revert to the round-13 configuration (best known: 244.9 us).
// A/B established: rot3-into-qkv fusion = +6us (co-compiled regalloc + mixed
// launch scheduling), attn setprio = +4us (4-wave lockstep = m190 null regime).
// Separate gemm_qkv / rot3_mfma launches, no setprio.

typedef __attribute__((ext_vector_type(8))) short short8;
typedef __attribute__((ext_vector_type(4))) float f32x4;
typedef unsigned short ushort_t;

__device__ __forceinline__ ushort_t f2b(float f) {
  union { float f; unsigned u; } x; x.f = f;
  unsigned r = x.u + 0x7fffu + ((x.u >> 16) & 1u);
  return (ushort_t)(r >> 16);
}
__device__ __forceinline__ float b2f(unsigned b) {
  union { unsigned u; float f; } x; x.u = b << 16;
  return x.f;
}
__device__ __forceinline__ void gload16(void* lds, const void* gp) {
  __builtin_amdgcn_global_load_lds(
      (const __attribute__((address_space(1))) unsigned int*)gp,
      (__attribute__((address_space(3))) unsigned int*)lds, 16, 0, 0);
}

// -------- fused prep: split_x | transpose_cvt x3 | w2_split | mcount=0 --------
__global__ __launch_bounds__(256) void prep_kernel(
    const float* __restrict__ x, const float* __restrict__ w_qk,
    const float* __restrict__ b_qk, const float* __restrict__ R,
    const float* __restrict__ w_v, const float* __restrict__ w_out,
    ushort_t* __restrict__ xh, ushort_t* __restrict__ xl,
    ushort_t* __restrict__ wqkT, ushort_t* __restrict__ wvT, ushort_t* __restrict__ woT,
    ushort_t* __restrict__ W2Th, ushort_t* __restrict__ W2Tl, float* __restrict__ b2,
    int* __restrict__ mcount)
{
  __shared__ float t[32][33];
  __shared__ float wrow[512];
  const int blk = blockIdx.x, tid = threadIdx.x;
  if (blk == 0 && tid == 0) mcount[0] = 0;

  if (blk < 4096) {                      // ---- split_x ----
    const int i = blk * 256 + tid;
    const float4 a = *(const float4*)(x + (size_t)i * 8);
    const float4 c = *(const float4*)(x + (size_t)i * 8 + 4);
    float v[8] = { a.x, a.y, a.z, a.w, c.x, c.y, c.z, c.w };
    ushort_t hi[8], lo[8];
    #pragma unroll
    for (int k = 0; k < 8; ++k) {
      hi[k] = f2b(v[k]);
      lo[k] = f2b(v[k] - b2f(hi[k]));
    }
    *(uint4*)(xh + (size_t)i * 8) = *(const uint4*)hi;
    *(uint4*)(xl + (size_t)i * 8) = *(const uint4*)lo;
  } else if (blk < 4864) {               // ---- transpose_cvt x3 ----
    const int idx = blk - 4096;
    const int mat = idx >> 8, r = idx & 255;
    const float* W  = (mat == 0) ? w_qk : (mat == 1) ? w_v : w_out;
    ushort_t*   Wt  = (mat == 0) ? wqkT : (mat == 1) ? wvT : woT;
    const int bx = (r & 15) * 32, by = (r >> 4) * 32;
    const int tx = tid & 31, ty = tid >> 5;
    #pragma unroll
    for (int j = 0; j < 4; ++j)
      t[ty + j*8][tx] = W[(size_t)(by + ty + j*8) * 512 + bx + tx];
    __syncthreads();
    #pragma unroll
    for (int j = 0; j < 4; ++j)
      Wt[(size_t)(bx + ty + j*8) * 512 + by + tx] = f2b(t[tx][ty + j*8]);
  } else {                               // ---- w2_split ----
    const int e = blk - 4864, j = tid;   // e in [0,513), j in [0,256)
    const float* src = (e < 512) ? (w_qk + (size_t)e * 512) : b_qk;
    wrow[j]       = src[j];
    wrow[j + 256] = src[j + 256];
    __syncthreads();
    float acc = 0.f;
    for (int f = 0; f < 512; ++f)
      acc = fmaf(wrow[f], R[(size_t)f * 256 + j], acc);
    if (e < 512) {
      const ushort_t hi = f2b(acc);
      W2Th[(size_t)j * 512 + e] = hi;
      W2Tl[(size_t)j * 512 + e] = f2b(acc - b2f(hi));
    } else {
      b2[j] = acc;
    }
  }
}

// ---- fused qk+v GEMM (1 product each), dbuf stage-ahead; out -> interleaved qkv ----
// grid (128, 8): y<4 -> qk col-block y; y>=4 -> v col-block y-4.
__global__ __launch_bounds__(256, 2) void gemm_qkv(
    const ushort_t* __restrict__ A, const ushort_t* __restrict__ wqkT,
    const ushort_t* __restrict__ wvT, const float* __restrict__ b_qk,
    const float* __restrict__ b_v, ushort_t* __restrict__ qkv)
{
  __shared__ __align__(16) char Al[32768];   // 2 x 16KB
  __shared__ __align__(16) char Bl[32768];
  const int bm = blockIdx.x * 128;
  const int sel = blockIdx.y >> 2;           // 0 = qk, 1 = v
  const int bn = (blockIdx.y & 3) * 128;
  const ushort_t* Wt   = sel ? wvT : wqkT;
  const float*    bias = sel ? b_v : b_qk;
  const int coff = sel * 512;
  const int tid = threadIdx.x, w = tid >> 6, l = tid & 63;
  const int m = l & 15, gq = l >> 4;
  f32x4 acc[2][8] = {};

#define STAGE1(NB, K0) { \
    _Pragma("unroll") \
    for (int j = 0; j < 4; ++j) { \
      const int row = w * 32 + j * 8 + (l >> 3); \
      const int ch = (l & 7) ^ (row & 7); \
      const int dst = (NB) * 16384 + w * 4096 + j * 1024 + l * 16; \
      gload16(Al + dst, A  + (size_t)(bm + row) * 512 + (K0) + ch * 8); \
      gload16(Bl + dst, Wt + (size_t)(bn + row) * 512 + (K0) + ch * 8); \
    } }

  STAGE1(0, 0)
  __syncthreads();
  for (int t = 0; t < 8; ++t) {
    const int cur = t & 1;
    if (t < 7) STAGE1(cur ^ 1, (t + 1) * 64)
    #pragma unroll
    for (int ks = 0; ks < 2; ++ks) {
      short8 bfr[8];
      #pragma unroll
      for (int tj = 0; tj < 8; ++tj) {
        const int brow = tj * 16 + m;
        bfr[tj] = *(const short8*)(Bl + cur * 16384 + ((brow * 128 + ks * 64 + gq * 16) ^ ((brow & 7) << 4)));
      }
      #pragma unroll
      for (int ti = 0; ti < 2; ++ti) {
        const int arow = w * 32 + ti * 16 + m;
        const short8 af = *(const short8*)(Al + cur * 16384 + ((arow * 128 + ks * 64 + gq * 16) ^ ((arow & 7) << 4)));
        #pragma unroll
        for (int tj = 0; tj < 8; ++tj)
          acc[ti][tj] = __builtin_amdgcn_mfma_f32_16x16x32_bf16(af, bfr[tj], acc[ti][tj], 0, 0, 0);
      }
    }
    __syncthreads();
  }
#undef STAGE1
  #pragma unroll
  for (int ti = 0; ti < 2; ++ti)
    #pragma unroll
    for (int tj = 0; tj < 8; ++tj) {
      const int col = bn + tj * 16 + m;
      const float bvv = bias[col];
      #pragma unroll
      for (int r2 = 0; r2 < 4; ++r2) {
        const int row = bm + w * 32 + ti * 16 + gq * 4 + r2;
        qkv[(size_t)row * 1024 + coff + col] = f2b(acc[ti][tj][r2] + bvv);
      }
    }
}

// ---- bf16 MFMA GEMM (1 product), dbuf; used for the out GEMM (fp32 out) ----
__global__ __launch_bounds__(256, 2) void gemm_mfma(
    const ushort_t* __restrict__ A, const ushort_t* __restrict__ Wt,
    const float* __restrict__ bias, float* __restrict__ Cf)
{
  __shared__ __align__(16) char Al[32768];
  __shared__ __align__(16) char Bl[32768];
  const int bm = blockIdx.x * 128, bn = blockIdx.y * 128;
  const int tid = threadIdx.x, w = tid >> 6, l = tid & 63;
  const int m = l & 15, gq = l >> 4;
  f32x4 acc[2][8] = {};

#define STAGE1(NB, K0) { \
    _Pragma("unroll") \
    for (int j = 0; j < 4; ++j) { \
      const int row = w * 32 + j * 8 + (l >> 3); \
      const int ch = (l & 7) ^ (row & 7); \
      const int dst = (NB) * 16384 + w * 4096 + j * 1024 + l * 16; \
      gload16(Al + dst, A  + (size_t)(bm + row) * 512 + (K0) + ch * 8); \
      gload16(Bl + dst, Wt + (size_t)(bn + row) * 512 + (K0) + ch * 8); \
    } }

  STAGE1(0, 0)
  __syncthreads();
  for (int t = 0; t < 8; ++t) {
    const int cur = t & 1;
    if (t < 7) STAGE1(cur ^ 1, (t + 1) * 64)
    #pragma unroll
    for (int ks = 0; ks < 2; ++ks) {
      short8 bfr[8];
      #pragma unroll
      for (int tj = 0; tj < 8; ++tj) {
        const int brow = tj * 16 + m;
        bfr[tj] = *(const short8*)(Bl + cur * 16384 + ((brow * 128 + ks * 64 + gq * 16) ^ ((brow & 7) << 4)));
      }
      #pragma unroll
      for (int ti = 0; ti < 2; ++ti) {
        const int arow = w * 32 + ti * 16 + m;
        const short8 af = *(const short8*)(Al + cur * 16384 + ((arow * 128 + ks * 64 + gq * 16) ^ ((arow & 7) << 4)));
        #pragma unroll
        for (int tj = 0; tj < 8; ++tj)
          acc[ti][tj] = __builtin_amdgcn_mfma_f32_16x16x32_bf16(af, bfr[tj], acc[ti][tj], 0, 0, 0);
      }
    }
    __syncthreads();
  }
#undef STAGE1
  #pragma unroll
  for (int ti = 0; ti < 2; ++ti)
    #pragma unroll
    for (int tj = 0; tj < 8; ++tj) {
      const int col = bn + tj * 16 + m;
      const float bvv = bias[col];
      #pragma unroll
      for (int r2 = 0; r2 < 4; ++r2) {
        const int row = bm + w * 32 + ti * 16 + gq * 4 + r2;
        Cf[(size_t)row * 512 + col] = acc[ti][tj][r2] + bvv;
      }
    }
}

// ---- rot = (xh+xl)@(W2h+W2l)^T + b2 via 3 MFMA products (lo*lo dropped), fp32 ----
__global__ __launch_bounds__(256, 2) void rot3_mfma(
    const ushort_t* __restrict__ Ah, const ushort_t* __restrict__ Al,
    const ushort_t* __restrict__ Bh, const ushort_t* __restrict__ Bl,
    const float* __restrict__ b2, float* __restrict__ rot)
{
  __shared__ __align__(16) char AH[16384], AL[16384], BH[16384], BL[16384];
  const int bm = blockIdx.x * 128, bn = blockIdx.y * 128;
  const int tid = threadIdx.x, w = tid >> 6, l = tid & 63;
  const int m = l & 15, gq = l >> 4;
  f32x4 acc[2][8] = {};
  for (int k0 = 0; k0 < 512; k0 += 64) {
    #pragma unroll
    for (int j = 0; j < 4; ++j) {
      const int row = w * 32 + j * 8 + (l >> 3);
      const int ch = (l & 7) ^ (row & 7);
      const int dst = w * 4096 + j * 1024 + l * 16;
      gload16(AH + dst, Ah + (size_t)(bm + row) * 512 + k0 + ch * 8);
      gload16(AL + dst, Al + (size_t)(bm + row) * 512 + k0 + ch * 8);
      gload16(BH + dst, Bh + (size_t)(bn + row) * 512 + k0 + ch * 8);
      gload16(BL + dst, Bl + (size_t)(bn + row) * 512 + k0 + ch * 8);
    }
    __syncthreads();
    #pragma unroll
    for (int ks = 0; ks < 2; ++ks) {
      short8 bh8[8], bl8[8];
      #pragma unroll
      for (int tj = 0; tj < 8; ++tj) {
        const int ba = ((tj * 16 + m) * 128 + ks * 64 + gq * 16) ^ (((tj * 16 + m) & 7) << 4);
        bh8[tj] = *(const short8*)(BH + ba);
        bl8[tj] = *(const short8*)(BL + ba);
      }
      #pragma unroll
      for (int ti = 0; ti < 2; ++ti) {
        const int arow = w * 32 + ti * 16 + m;
        const int aa = (arow * 128 + ks * 64 + gq * 16) ^ ((arow & 7) << 4);
        const short8 ah8 = *(const short8*)(AH + aa);
        const short8 al8 = *(const short8*)(AL + aa);
        #pragma unroll
        for (int tj = 0; tj < 8; ++tj) {
          acc[ti][tj] = __builtin_amdgcn_mfma_f32_16x16x32_bf16(ah8, bh8[tj], acc[ti][tj], 0, 0, 0);
          acc[ti][tj] = __builtin_amdgcn_mfma_f32_16x16x32_bf16(al8, bh8[tj], acc[ti][tj], 0, 0, 0);
          acc[ti][tj] = __builtin_amdgcn_mfma_f32_16x16x32_bf16(ah8, bl8[tj], acc[ti][tj], 0, 0, 0);
        }
      }
    }
    __syncthreads();
  }
  #pragma unroll
  for (int ti = 0; ti < 2; ++ti)
    #pragma unroll
    for (int tj = 0; tj < 8; ++tj) {
      const int col = bn + tj * 16 + m;
      const float bvv = b2[col];
      #pragma unroll
      for (int r2 = 0; r2 < 4; ++r2) {
        const int row = bm + w * 32 + ti * 16 + gq * 4 + r2;
        rot[(size_t)row * 256 + col] = acc[ti][tj][r2] + bvv;
      }
    }
}

// ---- fused: argmax+margin (blocks < 16384) | scale (blocks >= 16384) ----
__global__ __launch_bounds__(256) void argmax_scale(
    const float* __restrict__ rot, int* __restrict__ buckets,
    int* __restrict__ mlist, int* __restrict__ mcount, float tau,
    const ushort_t* __restrict__ qkv, float* __restrict__ scale)
{
  const int blk = blockIdx.x;
  if (blk < 16384) {
    const int tok = blk;
    const int j = threadIdx.x;             // j = h*32 + i
    const float r = rot[(size_t)tok * 256 + j];
    float m1, m2; int i1;
    if (r >= 0.f) { m1 = r;  i1 = j & 31;        m2 = -r; }
    else          { m1 = -r; i1 = (j & 31) + 32; m2 = r;  }
    #pragma unroll
    for (int off = 16; off; off >>= 1) {
      const float om1 = __shfl_xor(m1, off);
      const int   oi1 = __shfl_xor(i1, off);
      const float om2 = __shfl_xor(m2, off);
      float loser;
      if (om1 > m1 || (om1 == m1 && oi1 < i1)) { loser = m1; m1 = om1; i1 = oi1; }
      else loser = om1;
      m2 = fmaxf(fmaxf(m2, om2), loser);
    }
    if ((j & 31) == 0) {
      const int h = j >> 5, b = tok >> 12, t = tok & 4095;
      buckets[((b << 3) + h) * 4096 + t] = i1;
      if (m1 - m2 < tau) {
        const int k = atomicAdd(mcount, 1);
        mlist[k] = (((b << 3) + h) << 12) | t;
      }
    }
  } else {
    const int wave = threadIdx.x >> 6, lane = threadIdx.x & 63;
    const int tok = (blk - 16384) * 4 + wave;
    const uint4 H = *(const uint4*)(qkv + (size_t)tok * 1024 + lane * 8);
    const unsigned* hp = (const unsigned*)&H;
    float s = 0.f;
    #pragma unroll
    for (int e = 0; e < 4; ++e) {
      const float v0 = b2f(hp[e] & 0xffffu);
      const float v1 = b2f(hp[e] >> 16);
      s += v0 * v0 + v1 * v1;
    }
    #pragma unroll
    for (int off = 32; off; off >>= 1) s += __shfl_down(s, off);
    if (lane == 0) {
      const float nn = fmaxf(sqrtf(s), 1e-12f);
      scale[tok] = 0.044194173824159216f / nn;   // 512^-0.5 / norm
    }
  }
}

// ---- exact np-chain fallback for marginal (b,h,t) pairs ----
__global__ __launch_bounds__(512) void bucket_fallback(
    const float* __restrict__ x, const float* __restrict__ w_qk,
    const float* __restrict__ b_qk, const float* __restrict__ R,
    const int* __restrict__ mlist, const int* __restrict__ mcount,
    int* __restrict__ buckets)
{
  __shared__ float qkrow[512];
  const int n = mcount[0];
  for (int ii = blockIdx.x; ii < n; ii += gridDim.x) {
    const int mm = mlist[ii];
    const int bh = mm >> 12, t = mm & 4095;
    const int b = bh >> 3, h = bh & 7;
    const float* xr = x + ((size_t)b * 4096 + t) * 512;
    {
      const int c = threadIdx.x;
      float a0 = 0.f;
      for (int f = 0; f < 512; ++f) a0 = fmaf(xr[f], w_qk[(size_t)f * 512 + c], a0);
      qkrow[c] = a0 + b_qk[c];
    }
    __syncthreads();
    if (threadIdx.x < 32) {
      const int col = h * 32 + threadIdx.x;
      float a0 = 0.f;
      for (int f = 0; f < 512; ++f) a0 = fmaf(qkrow[f], R[(size_t)f * 256 + col], a0);
      float m1; int i1;
      if (a0 >= 0.f) { m1 = a0;  i1 = threadIdx.x; }
      else           { m1 = -a0; i1 = threadIdx.x + 32; }
      #pragma unroll
      for (int off = 16; off; off >>= 1) {
        const float om = __shfl_xor(m1, off);
        const int   oi = __shfl_xor(i1, off);
        if (om > m1 || (om == m1 && oi < i1)) { m1 = om; i1 = oi; }
      }
      if (threadIdx.x == 0) buckets[(size_t)bh * 4096 + t] = i1;
    }
    __syncthreads();
  }
}

// -------- stable counting sort per (b,h), wave-parallel via 6-ballot match --------
__global__ __launch_bounds__(256) void sort_kernel(
    const int* __restrict__ buckets, int* __restrict__ st)
{
  __shared__ int bk_lds[4096];
  __shared__ int cnt[64][64];
  __shared__ int bstart[64];
  const int tid = threadIdx.x;
  const int base = blockIdx.x * 4096;     // blockIdx = b*8+h
  const int wave = tid >> 6, lane = tid & 63;
  const unsigned long long lt = (1ull << lane) - 1ull;

  for (int t = tid; t < 4096; t += 256) bk_lds[t] = buckets[base + t];
  for (int i = tid; i < 4096; i += 256) ((int*)cnt)[i] = 0;
  __syncthreads();

  for (int c = wave; c < 64; c += 4) {
    const int bk = bk_lds[c * 64 + lane];
    unsigned long long mask = ~0ull;
    #pragma unroll
    for (int bit = 0; bit < 6; ++bit) {
      const unsigned long long bb = __ballot((bk >> bit) & 1);
      mask &= ((bk >> bit) & 1) ? bb : ~bb;
    }
    if ((mask & lt) == 0)
      cnt[c][bk] = __popcll(mask);
  }
  __syncthreads();

  if (tid < 64) {
    int run = 0;
    for (int c = 0; c < 64; ++c) {
      const int v = cnt[c][tid];
      cnt[c][tid] = run;
      run += v;
    }
    int ex = run;
    #pragma unroll
    for (int off = 1; off < 64; off <<= 1) {
      const int nn = __shfl_up(ex, off);
      if (lane >= off) ex += nn;
    }
    bstart[tid] = ex - run;
  }
  __syncthreads();

  for (int c = wave; c < 64; c += 4) {
    const int tok = c * 64 + lane;
    const int bk = bk_lds[tok];
    unsigned long long mask = ~0ull;
    #pragma unroll
    for (int bit = 0; bit < 6; ++bit) {
      const unsigned long long bb = __ballot((bk >> bit) & 1);
      mask &= ((bk >> bit) & 1) ? bb : ~bb;
    }
    const int rank = (int)__popcll(mask & lt);
    st[base + bstart[bk] + cnt[c][bk] + rank] = tok;
  }
}

// -------- MFMA chunked attention: interleaved qkv input, T14 stage-ahead --------
__global__ __launch_bounds__(256, 2) void attn_mfma(
    const ushort_t* __restrict__ qkv, const float* __restrict__ scale,
    const int* __restrict__ st, ushort_t* __restrict__ so, int g, int hbase)
{
  __shared__ __align__(16) char Q[32768];
  __shared__ __align__(16) char VT[32768];
  __shared__ __align__(16) char P[8192];
  __shared__ int   stt[64];
  __shared__ float scl[64];

  const int blk = blockIdx.x;
  const int cpg = g * 64;
  const int b = blk / cpg, rem = blk % cpg;
  const int hl = rem >> 6, c = rem & 63;
  const int tid = threadIdx.x, w = tid >> 6, l = tid & 63;
  const int m = l & 15, gq = l >> 4;
  const int srow = tid >> 5, su = tid & 31;

  if (tid < 64) {
    const int s = st[(size_t)((b * 8 + hbase + hl) * 4096) + c * 64 + tid];
    stt[tid] = s;
    scl[tid] = scale[b * 4096 + s];
  }
  __syncthreads();

  const size_t qkbase = (size_t)b * 4096;
  uint4 rg[8];

#define LOADG(VOFF, HALF) { \
    _Pragma("unroll") \
    for (int it = 0; it < 8; ++it) { \
      const int row = it * 8 + srow; \
      rg[it] = *(const uint4*)(qkv + (qkbase + stt[row]) * 1024 + (VOFF) + (HALF) * 256 + su * 8); \
    } }
#define WRITEQ() { \
    _Pragma("unroll") \
    for (int it = 0; it < 8; ++it) { \
      const int row = it * 8 + srow; \
      *(uint4*)(Q + ((row * 512 + su * 16) ^ ((row & 7) << 4))) = rg[it]; \
    } }
#define WRITEVT() { \
    _Pragma("unroll") \
    for (int it = 0; it < 8; ++it) { \
      const int j = it * 8 + srow; \
      const ushort_t* e = (const ushort_t*)&rg[it]; \
      _Pragma("unroll") \
      for (int ee = 0; ee < 8; ++ee) { \
        const int d = su * 8 + ee; \
        *(ushort_t*)(VT + ((d * 128 + j * 2) ^ (((d ^ (d >> 3)) & 7) << 4))) = e[ee]; \
      } \
    } }
#define COMPUTE_S() { \
    _Pragma("unroll") \
    for (int kf = 0; kf < 8; ++kf) { \
      const int arow = w * 16 + m; \
      const short8 af = *(const short8*)(Q + ((arow * 512 + kf * 64 + gq * 16) ^ ((arow & 7) << 4))); \
      _Pragma("unroll") \
      for (int jt = 0; jt < 4; ++jt) { \
        const int brow = jt * 16 + m; \
        const short8 bf = *(const short8*)(Q + ((brow * 512 + kf * 64 + gq * 16) ^ ((brow & 7) << 4))); \
        accS[jt] = __builtin_amdgcn_mfma_f32_16x16x32_bf16(af, bf, accS[jt], 0, 0, 0); \
      } \
    } }
#define COMPUTE_PV(ACCO) { \
    _Pragma("unroll") \
    for (int dt = 0; dt < 16; ++dt) { \
      _Pragma("unroll") \
      for (int kf = 0; kf < 2; ++kf) { \
        const int d = dt * 16 + m; \
        const short8 bv = *(const short8*)(VT + ((d * 128 + kf * 64 + gq * 16) ^ (((d ^ (d >> 3)) & 7) << 4))); \
        ACCO[dt] = __builtin_amdgcn_mfma_f32_16x16x32_bf16(ap[kf], bv, ACCO[dt], 0, 0, 0); \
      } \
    } }
#define BOUNCE(ACCO) { \
    _Pragma("unroll") \
    for (int dt = 0; dt < 16; ++dt) \
      _Pragma("unroll") \
      for (int r = 0; r < 4; ++r) { \
        const int i = w * 16 + gq * 4 + r; \
        const int dcol = dt * 16 + m; \
        *(ushort_t*)(Q + ((i * 512 + dcol * 2) ^ ((i & 7) << 4))) = f2b(ACCO[dt][r]); \
      } }
#define FLUSH(HALF) { \
    _Pragma("unroll") \
    for (int it = 0; it < 8; ++it) { \
      const int row = it * 8 + srow; \
      const uint4 dat = *(const uint4*)(Q + ((row * 512 + su * 16) ^ ((row & 7) << 4))); \
      *(uint4*)(so + (sobase + stt[row]) * 512 + (HALF) * 256 + su * 8) = dat; \
    } }

  f32x4 accS[4] = {};

  LOADG(0, 0)
  WRITEQ()
  __syncthreads();
  LOADG(0, 1)
  COMPUTE_S()
  __syncthreads();
  WRITEQ()
  __syncthreads();
  LOADG(512, 0)
  COMPUTE_S()
  __syncthreads();

  #pragma unroll
  for (int jt = 0; jt < 4; ++jt)
    #pragma unroll
    for (int r = 0; r < 4; ++r) {
      const int i = w * 16 + gq * 4 + r;
      const int j = jt * 16 + m;
      *(ushort_t*)(P + ((i * 128 + j * 2) ^ ((i & 7) << 4))) = f2b(accS[jt][r] * scl[j]);
    }
  WRITEVT()
  __syncthreads();

  const size_t sobase = (size_t)(b * g + hl) * 4096;
  LOADG(512, 1)
  short8 ap[2];
  #pragma unroll
  for (int kf = 0; kf < 2; ++kf) {
    const int i = w * 16 + m;
    ap[kf] = *(const short8*)(P + ((i * 128 + kf * 64 + gq * 16) ^ ((i & 7) << 4)));
  }
  f32x4 accO[16] = {};
  COMPUTE_PV(accO)
  __syncthreads();

  WRITEVT()
  BOUNCE(accO)
  __syncthreads();

  FLUSH(0)
  f32x4 accO2[16] = {};
  COMPUTE_PV(accO2)
  __syncthreads();

  BOUNCE(accO2)
  __syncthreads();
  FLUSH(1)

#undef LOADG
#undef WRITEQ
#undef WRITEVT
#undef COMPUTE_S
#undef COMPUTE_PV
#undef BOUNCE
#undef FLUSH
}

// -------- gather: o_b[tok][:] (+)= sum_{hl<g} so[(b*g+hl)*4096 + t][:], bf16 --------
__global__ __launch_bounds__(256) void gather_kernel(
    const ushort_t* __restrict__ so, ushort_t* __restrict__ o_b, int g, int first)
{
  const int tok = blockIdx.x;
  const int b = tok >> 12, t = tok & 4095;
  const int d0 = threadIdx.x * 2;
  ushort_t* dst = o_b + (size_t)tok * 512 + d0;
  float ax = 0.f, ay = 0.f;
  if (!first) {
    const unsigned u = *(const unsigned*)dst;
    ax = b2f(u & 0xffffu); ay = b2f(u >> 16);
  }
  const size_t stride = (size_t)4096 * 512;
  const ushort_t* src = so + ((size_t)(b * g) * 4096 + t) * 512 + d0;
  for (int hlp = 0; hlp < g; ++hlp) {
    const unsigned u = *(const unsigned*)src;
    ax += b2f(u & 0xffffu);
    ay += b2f(u >> 16);
    src += stride;
  }
  *(unsigned*)dst = ((unsigned)f2b(ay) << 16) | (unsigned)f2b(ax);
}

extern "C" void kernel_launch(void* const* d_in, const int* in_sizes, int n_in,
                              void* d_out, int out_size, void* d_ws, size_t ws_size,
                              hipStream_t stream) {
  const float* x         = (const float*)d_in[0];
  const float* rotations = (const float*)d_in[1];
  const float* w_qk      = (const float*)d_in[2];
  const float* b_qk      = (const float*)d_in[3];
  const float* w_v       = (const float*)d_in[4];
  const float* b_v       = (const float*)d_in[5];
  const float* w_out     = (const float*)d_in[6];
  const float* b_out     = (const float*)d_in[7];
  float* out = (float*)d_out;
  char* ws = (char*)d_ws;

  ushort_t* xh      = (ushort_t*)(ws);                  // 16.78 MB
  ushort_t* xl      = (ushort_t*)(ws + 16777216);       // 16.78 MB
  ushort_t* qkv     = (ushort_t*)(ws + 33554432);       // 33.55 MB (qk|v interleaved, 2KB/token)
  float*    rot     = (float*)(ws + 67108864);          // 16.78 MB (dead after fallback)
  ushort_t* o_b     = (ushort_t*)(ws + 67108864);       // alias: lives after gather
  ushort_t* wqkTh   = (ushort_t*)(ws + 83886080);       // 512 KB
  ushort_t* wvT     = (ushort_t*)(ws + 84410368);       // 512 KB
  ushort_t* woT     = (ushort_t*)(ws + 84934656);       // 512 KB
  ushort_t* W2Th    = (ushort_t*)(ws + 85458944);       // 256 KB
  ushort_t* W2Tl    = (ushort_t*)(ws + 85721088);       // 256 KB
  float*    b2      = (float*)(ws + 85983232);          // 1 KB (pad to 4K)
  float*    scale   = (float*)(ws + 85987328);          // 64 KB
  int*      buckets = (int*)(ws + 86052864);            // 512 KB
  int*      st      = (int*)(ws + 86577152);            // 512 KB
  int*      mlist   = (int*)(ws + 87101440);            // 512 KB (cap 131072: can't overflow)
  int*      mcount  = (int*)(ws + 87625728);            // 4 KB
  ushort_t* so      = (ushort_t*)(ws + 87629824);       // g * 16.78 MB
  const size_t so_off = 87629824;

  int g = 1;
  for (int cand = 8; cand >= 1; cand >>= 1)
    if (so_off + (size_t)cand * 16777216ull <= ws_size) { g = cand; break; }

  const dim3 blk256(256);
  hipLaunchKernelGGL(prep_kernel, dim3(5377), blk256, 0, stream,
                     x, w_qk, b_qk, rotations, w_v, w_out,
                     xh, xl, wqkTh, wvT, woT, W2Th, W2Tl, b2, mcount);

  hipLaunchKernelGGL(gemm_qkv, dim3(128, 8), blk256, 0, stream, xh, wqkTh, wvT, b_qk, b_v, qkv);
  hipLaunchKernelGGL(rot3_mfma, dim3(128, 2), blk256, 0, stream, xh, xl, W2Th, W2Tl, b2, rot);

  hipLaunchKernelGGL(argmax_scale, dim3(20480), blk256, 0, stream,
                     rot, buckets, mlist, mcount, 1.5e-3f, qkv, scale);
  hipLaunchKernelGGL(bucket_fallback, dim3(1024), dim3(512), 0, stream,
                     x, w_qk, b_qk, rotations, mlist, mcount, buckets);
  hipLaunchKernelGGL(sort_kernel, dim3(32), blk256, 0, stream, buckets, st);

  const int passes = 8 / g;
  for (int p = 0; p < passes; ++p) {
    const int hbase = p * g;
    hipLaunchKernelGGL(attn_mfma, dim3(4 * g * 64), blk256, 0, stream,
                       qkv, scale, st, so, g, hbase);
    hipLaunchKernelGGL(gather_kernel, dim3(16384), blk256, 0, stream,
                       so, o_b, g, (p == 0) ? 1 : 0);
  }

  hipLaunchKernelGGL(gemm_mfma, dim3(128, 4), blk256, 0, stream, o_b, woT, b_out, out);
}